// Round 4
// baseline (21337.770 us; speedup 1.0000x reference)
//
#include <hip/hip_runtime.h>
#include <cstdint>

typedef unsigned long long u64;

static __device__ __forceinline__ float leakyf(float v) { return v >= 0.f ? v : 0.2f * v; }

// ------------------------------------------------------------------
// Pack [M,3] positions into float4(x,y,z,|p|^2). ss association (x*x+y*y)+z*z
// must match the query-side qq usage in knn/three_nn.
__global__ void pack_kernel(const float* __restrict__ pos, int total, float4* __restrict__ out)
{
  int i = blockIdx.x * 256 + threadIdx.x;
  if (i >= total) return;
  float x = pos[i*3+0], y = pos[i*3+1], z = pos[i*3+2];
  out[i] = make_float4(x, y, z, (x*x + y*y) + z*z);
}

// ------------------------------------------------------------------
static __device__ __forceinline__ unsigned part1by2(unsigned v)
{
  v &= 0x3FFu;
  v = (v | (v << 16)) & 0x030000FFu;
  v = (v | (v << 8))  & 0x0300F00Fu;
  v = (v | (v << 4))  & 0x030C30C3u;
  v = (v | (v << 2))  & 0x09249249u;
  return v;
}

// FPS prep: Morton-sort points into 64-point spatial groups; emit sorted coords,
// tie-break payload iv = 0xFFFFFFFF - orig_idx, group bounding spheres (center,
// radius upper bound), initial group keys (dist=1e10, smallest orig idx) and
// prune thresholds aux = (sqrt(gmax)+r)^2 * margin.
// Correctness only needs: (a) sort is a permutation (bitonic swaps guarantee),
// (b) r is a true upper bound (inflated 1.0001). Morton quality affects speed only.
template<int N>
__global__ __launch_bounds__(512) void fps_prep_kernel(const float* __restrict__ pos,
    float* __restrict__ sxp, float* __restrict__ syp, float* __restrict__ szp,
    unsigned* __restrict__ ivg, float4* __restrict__ gcg,
    u64* __restrict__ gk0, float* __restrict__ ax0)
{
  constexpr int NG = N / 64;
  const int b = blockIdx.x;
  const float* P = pos + (size_t)b * N * 3;
  float* SX = sxp + (size_t)b * N;
  float* SY = syp + (size_t)b * N;
  float* SZ = szp + (size_t)b * N;
  unsigned* IV = ivg + (size_t)b * N;
  float4* GC = gcg + (size_t)b * NG;
  u64* GK = gk0 + (size_t)b * NG;
  float* AX = ax0 + (size_t)b * NG;

  __shared__ u64 skey[N];
  __shared__ float sred[512];
  const int t = threadIdx.x;

  // cloud bbox
  float mn[3] = {3.4e38f, 3.4e38f, 3.4e38f};
  float mx[3] = {-3.4e38f, -3.4e38f, -3.4e38f};
  for (int i = t; i < N; i += 512) {
    float c3[3] = {P[i*3], P[i*3+1], P[i*3+2]};
#pragma unroll
    for (int a = 0; a < 3; ++a) { mn[a] = fminf(mn[a], c3[a]); mx[a] = fmaxf(mx[a], c3[a]); }
  }
  float bmin[3], inv[3];
  for (int a = 0; a < 3; ++a) {
    sred[t] = mn[a]; __syncthreads();
    for (int s = 256; s > 0; s >>= 1) { if (t < s) sred[t] = fminf(sred[t], sred[t+s]); __syncthreads(); }
    bmin[a] = sred[0]; __syncthreads();
    sred[t] = mx[a]; __syncthreads();
    for (int s = 256; s > 0; s >>= 1) { if (t < s) sred[t] = fmaxf(sred[t], sred[t+s]); __syncthreads(); }
    float bmax = sred[0]; __syncthreads();
    inv[a] = 1023.0f / fmaxf(bmax - bmin[a], 1e-20f);
  }
  // morton keys
  for (int i = t; i < N; i += 512) {
    float x = P[i*3], y = P[i*3+1], z = P[i*3+2];
    unsigned cx = (unsigned)fminf(fmaxf((x - bmin[0]) * inv[0], 0.f), 1023.f);
    unsigned cy = (unsigned)fminf(fmaxf((y - bmin[1]) * inv[1], 0.f), 1023.f);
    unsigned cz = (unsigned)fminf(fmaxf((z - bmin[2]) * inv[2], 0.f), 1023.f);
    unsigned code = part1by2(cx) | (part1by2(cy) << 1) | (part1by2(cz) << 2);
    skey[i] = ((u64)code << 32) | (unsigned)i;
  }
  __syncthreads();
  // in-LDS bitonic sort, ascending
  for (int k = 2; k <= N; k <<= 1)
    for (int j = k >> 1; j > 0; j >>= 1) {
      for (int i = t; i < N; i += 512) {
        int ixj = i ^ j;
        if (ixj > i) {
          u64 a = skey[i], c = skey[ixj];
          if ((a > c) == ((i & k) == 0)) { skey[i] = c; skey[ixj] = a; }
        }
      }
      __syncthreads();
    }
  // sorted coordinate arrays + payload
  for (int i = t; i < N; i += 512) {
    unsigned orig = (unsigned)(skey[i] & 0xFFFFFFFFull);
    SX[i] = P[orig*3]; SY[i] = P[orig*3+1]; SZ[i] = P[orig*3+2];
    IV[i] = 0xFFFFFFFFu - orig;
  }
  // group stats: one wave per group
  const int wv = t >> 6, lane = t & 63;
  for (int g = wv; g < NG; g += 8) {
    int sp = g * 64 + lane;
    unsigned orig = (unsigned)(skey[sp] & 0xFFFFFFFFull);
    float x = P[orig*3], y = P[orig*3+1], z = P[orig*3+2];
    float lx = x, hx = x, ly = y, hy = y, lz = z, hz = z;
#pragma unroll
    for (int s = 1; s < 64; s <<= 1) {
      lx = fminf(lx, __shfl_xor(lx, s)); hx = fmaxf(hx, __shfl_xor(hx, s));
      ly = fminf(ly, __shfl_xor(ly, s)); hy = fmaxf(hy, __shfl_xor(hy, s));
      lz = fminf(lz, __shfl_xor(lz, s)); hz = fmaxf(hz, __shfl_xor(hz, s));
    }
    float ccx = (lx+hx)*0.5f, ccy = (ly+hy)*0.5f, ccz = (lz+hz)*0.5f;
    float dx = x-ccx, dy = y-ccy, dz = z-ccz;
    float r2 = fmaf(dz, dz, fmaf(dy, dy, dx*dx));
    unsigned mo = orig;
#pragma unroll
    for (int s = 1; s < 64; s <<= 1) {
      r2 = fmaxf(r2, __shfl_xor(r2, s));
      unsigned o = __shfl_xor(mo, s); mo = o < mo ? o : mo;
    }
    if (lane == 0) {
      float r = sqrtf(r2) * 1.0001f;
      GC[g] = make_float4(ccx, ccy, ccz, r);
      GK[g] = ((u64)__float_as_uint(1e10f) << 32) | (u64)(0xFFFFFFFFu - mo);
      float s0 = sqrtf(1e10f) + r;
      AX[g] = s0 * s0 * 1.0001f;
    }
  }
}

// ------------------------------------------------------------------
// Pruned FPS, exact. 256 threads (4 waves) per batch. Wave w owns groups g%4==w
// (Morton-interleaved for load balance). Per iter: prune test per group (sphere
// bound, conservative margin), update only non-pruned groups (min-dist + u64
// (d,iv) key reduce -> gkey/aux), barrier, redundant per-wave global max over
// gkeys, barrier. Selection sequence bit-identical to the dense version.
template<int N, int NPOINT>
__global__ __launch_bounds__(256) void fps_kernel(const float* __restrict__ pos,
    const float* __restrict__ sxp, const float* __restrict__ syp, const float* __restrict__ szp,
    const unsigned* __restrict__ ivg, const float4* __restrict__ gcg,
    const u64* __restrict__ gk0, const float* __restrict__ ax0,
    int* __restrict__ out_idx, float* __restrict__ out_pos, float4* __restrict__ out_pp)
{
  constexpr int NG = N / 64;
  constexpr int GPW = NG / 4;
  const int b = blockIdx.x;
  const float* P = pos + (size_t)b * N * 3;
  const float* SX = sxp + (size_t)b * N;
  const float* SY = syp + (size_t)b * N;
  const float* SZ = szp + (size_t)b * N;
  const unsigned* IV = ivg + (size_t)b * N;
  const float4* GC = gcg + (size_t)b * NG;
  const u64* GK0 = gk0 + (size_t)b * NG;
  const float* AX0 = ax0 + (size_t)b * NG;
  int* oi = out_idx + (size_t)b * NPOINT;
  float* op = out_pos + (size_t)b * NPOINT * 3;
  float4* opp = out_pp + (size_t)b * NPOINT;

  __shared__ float sx[N], sy[N], sz[N], dist[N];
  __shared__ float4 gc[NG];
  __shared__ u64 gkey[NG];
  __shared__ float aux[NG];

  const int t = threadIdx.x, lane = t & 63, wv = t >> 6;
  for (int i = t; i < N; i += 256) { sx[i] = SX[i]; sy[i] = SY[i]; sz[i] = SZ[i]; dist[i] = 1e10f; }
  for (int g = t; g < NG; g += 256) { gc[g] = GC[g]; gkey[g] = GK0[g]; aux[g] = AX0[g]; }
  if (t == 0) oi[0] = 0;
  __syncthreads();

  int far = 0;
  for (int it = 1; it < NPOINT; ++it) {
    const int fs = __builtin_amdgcn_readfirstlane(far);
    const float cx = P[fs*3+0], cy = P[fs*3+1], cz = P[fs*3+2];
    if (t == 0) {  // emit sample it-1 (its coords are the current center)
      op[(it-1)*3+0] = cx; op[(it-1)*3+1] = cy; op[(it-1)*3+2] = cz;
      opp[it-1] = make_float4(cx, cy, cz, (cx*cx + cy*cy) + cz*cz);
    }
    // prune phase: lane l < GPW tests group l*4 + wv
    bool need = false;
    if (lane < GPW) {
      int g = (lane << 2) + wv;
      float4 gv = gc[g];
      float dxg = cx - gv.x, dyg = cy - gv.y, dzg = cz - gv.z;
      float dd = fmaf(dzg, dzg, fmaf(dyg, dyg, dxg*dxg));
      need = dd < aux[g];
    }
    unsigned mask = (unsigned)__ballot(need);
    mask = __builtin_amdgcn_readfirstlane(mask);
    while (mask) {
      const int j = __builtin_ctz(mask); mask &= mask - 1;
      const int g = (j << 2) + wv;
      const int sp = (g << 6) + lane;
      const unsigned ivv = IV[sp];               // read-only payload (global, L2-hot)
      const float x = sx[sp], y = sy[sp], z = sz[sp], dv = dist[sp];
      float ddx = x - cx, ddy = y - cy, ddz = z - cz;
      float d  = fmaf(ddz, ddz, fmaf(ddy, ddy, ddx * ddx));  // EXACT formula as dense version
      float nd = fminf(dv, d);
      dist[sp] = nd;
      u64 key = ((u64)__float_as_uint(nd) << 32) | (u64)ivv;
#pragma unroll
      for (int s = 1; s < 64; s <<= 1) { u64 o = __shfl_xor(key, s); if (o > key) key = o; }
      if (lane == 0) {
        gkey[g] = key;
        float gm = __uint_as_float((unsigned)(key >> 32));
        float sr = sqrtf(gm) + gc[g].w;
        aux[g] = sr * sr * 1.0001f;              // conservative: covers all f32 rounding
      }
    }
    __syncthreads();
    // global argmax over group keys (each wave redundantly -> no broadcast)
    u64 k0 = gkey[lane];
    if constexpr (NG > 64) { u64 k1 = gkey[lane + 64]; if (k1 > k0) k0 = k1; }
#pragma unroll
    for (int s = 1; s < 64; s <<= 1) { u64 o = __shfl_xor(k0, s); if (o > k0) k0 = o; }
    far = (int)(0xFFFFFFFFu - (unsigned)(k0 & 0xFFFFFFFFull));
    if (t == 0) oi[it] = far;
    __syncthreads();  // protect gkey reads from next iteration's writes
  }
  // flush last sample
  {
    const int fs = __builtin_amdgcn_readfirstlane(far);
    if (t == 0) {
      float cx = P[fs*3+0], cy = P[fs*3+1], cz = P[fs*3+2];
      op[(NPOINT-1)*3+0] = cx; op[(NPOINT-1)*3+1] = cy; op[(NPOINT-1)*3+2] = cz;
      opp[NPOINT-1] = make_float4(cx, cy, cz, (cx*cx + cy*cy) + cz*cz);
    }
  }
}

// ------------------------------------------------------------------
// Self-KNN (K=16), stable (d, idx) selection identical to lax.top_k(-d).
// G=16 segments per query; per-seg sorted top-16 in registers; segments merged
// in-wave via shfl_xor bitonic rounds with lexicographic (d, idx) comparator.
template<int G>
__global__ __launch_bounds__(256) void knn_kernel(const float4* __restrict__ pp, int M,
                                                  int* __restrict__ out)
{
  const int b = blockIdx.y;
  const float4* P = pp + (size_t)b * M;
  const int tid = threadIdx.x;
  constexpr int QPB = 256 / G;
  const int q = blockIdx.x * QPB + tid / G;
  const int seg = tid % G;

  __shared__ float4 tile[512];

  const float4 qp = P[q];
  const float qx = qp.x, qy = qp.y, qz = qp.z, qq = qp.w;

  float a[16]; int id[16];
#pragma unroll
  for (int j = 0; j < 16; ++j) { a[j] = 3.4e38f; id[j] = 0x7fffffff; }

  for (int t0 = 0; t0 < M; t0 += 512) {
    __syncthreads();
    tile[tid]       = P[t0 + tid];
    tile[tid + 256] = P[t0 + tid + 256];
    __syncthreads();
#pragma unroll 4
    for (int i = seg; i < 512; i += G) {
      float4 c = tile[i];
      float d = (qq + c.w) - 2.f * ((qx*c.x + qy*c.y) + qz*c.z);
      int gi = t0 + i;
      if (d < a[15]) {               // insertion, stable: ties keep earlier idx
        bool cc[16];
#pragma unroll
        for (int j = 0; j < 16; ++j) cc[j] = d < a[j];
#pragma unroll
        for (int j = 15; j >= 1; --j) {
          a[j]  = cc[j-1] ? a[j-1]  : (cc[j] ? d  : a[j]);
          id[j] = cc[j-1] ? id[j-1] : (cc[j] ? gi : id[j]);
        }
        if (cc[0]) { a[0] = d; id[0] = gi; }
      }
    }
  }
  // butterfly merge across G segments
#pragma unroll
  for (int s = G/2; s >= 1; s >>= 1) {
    float bd[16]; int bi[16];
#pragma unroll
    for (int j = 0; j < 16; ++j) { bd[j] = __shfl_xor(a[j], s); bi[j] = __shfl_xor(id[j], s); }
#pragma unroll
    for (int j = 0; j < 16; ++j) {       // lower half of bitonic 32-seq [a asc | b desc]
      float od = bd[15-j]; int ob = bi[15-j];
      bool take = (od < a[j]) || (od == a[j] && ob < id[j]);
      a[j]  = take ? od : a[j];
      id[j] = take ? ob : id[j];
    }
#pragma unroll
    for (int st = 8; st >= 1; st >>= 1) { // bitonic merge
#pragma unroll
      for (int j = 0; j < 16; ++j) {
        if ((j & st) == 0) {
          const int j2 = j + st;
          bool sw = (a[j2] < a[j]) || (a[j2] == a[j] && id[j2] < id[j]);
          float lod = sw ? a[j2] : a[j];  int loi = sw ? id[j2] : id[j];
          float hid = sw ? a[j]  : a[j2]; int hii = sw ? id[j]  : id[j2];
          a[j] = lod; id[j] = loi; a[j2] = hid; id[j2] = hii;
        }
      }
    }
  }
  if (seg == 0) {
    int* opp = out + ((size_t)b * M + q) * 16;
#pragma unroll
    for (int j = 0; j < 16; ++j) opp[j] = id[j];
  }
}

// ------------------------------------------------------------------
// three_nn + interpolation weights. Same G-segmented structure with register
// top-4 lists (4th slot only to make the bitonic trick power-of-two).
template<int G>
__global__ __launch_bounds__(256) void three_nn_kernel(const float4* __restrict__ qpp,
                                                       const float4* __restrict__ kpp,
                                                       int Mq, int Mk,
                                                       int* __restrict__ oidx, float* __restrict__ ow)
{
  const int b = blockIdx.y;
  const float4* Q  = qpp + (size_t)b * Mq;
  const float4* Kp = kpp + (size_t)b * Mk;
  const int tid = threadIdx.x;
  constexpr int QPB = 256 / G;
  const int q = blockIdx.x * QPB + tid / G;
  const int seg = tid % G;

  __shared__ float4 tile[512];

  const float4 qp = Q[q];
  const float qx = qp.x, qy = qp.y, qz = qp.z, qq = qp.w;

  float a[4]; int id[4];
#pragma unroll
  for (int j = 0; j < 4; ++j) { a[j] = 3.4e38f; id[j] = 0x7fffffff; }

  for (int t0 = 0; t0 < Mk; t0 += 512) {
    __syncthreads();
    tile[tid]       = Kp[t0 + tid];
    tile[tid + 256] = Kp[t0 + tid + 256];
    __syncthreads();
#pragma unroll 4
    for (int i = seg; i < 512; i += G) {
      float4 c = tile[i];
      float d = (qq + c.w) - 2.f * ((qx*c.x + qy*c.y) + qz*c.z);
      int gi = t0 + i;
      if (d < a[3]) {
        bool c0 = d < a[0], c1 = d < a[1], c2 = d < a[2];
        a[3]  = c2 ? a[2]  : d;                id[3] = c2 ? id[2] : gi;
        a[2]  = c1 ? a[1]  : (c2 ? d  : a[2]); id[2] = c1 ? id[1] : (c2 ? gi : id[2]);
        a[1]  = c0 ? a[0]  : (c1 ? d  : a[1]); id[1] = c0 ? id[0] : (c1 ? gi : id[1]);
        if (c0) { a[0] = d; id[0] = gi; }
      }
    }
  }
#pragma unroll
  for (int s = G/2; s >= 1; s >>= 1) {
    float bd[4]; int bi[4];
#pragma unroll
    for (int j = 0; j < 4; ++j) { bd[j] = __shfl_xor(a[j], s); bi[j] = __shfl_xor(id[j], s); }
#pragma unroll
    for (int j = 0; j < 4; ++j) {
      float od = bd[3-j]; int ob = bi[3-j];
      bool take = (od < a[j]) || (od == a[j] && ob < id[j]);
      a[j]  = take ? od : a[j];
      id[j] = take ? ob : id[j];
    }
#pragma unroll
    for (int st = 2; st >= 1; st >>= 1) {
#pragma unroll
      for (int j = 0; j < 4; ++j) {
        if ((j & st) == 0) {
          const int j2 = j + st;
          bool sw = (a[j2] < a[j]) || (a[j2] == a[j] && id[j2] < id[j]);
          float lod = sw ? a[j2] : a[j];  int loi = sw ? id[j2] : id[j];
          float hid = sw ? a[j]  : a[j2]; int hii = sw ? id[j]  : id[j2];
          a[j] = lod; id[j] = loi; a[j2] = hid; id[j2] = hii;
        }
      }
    }
  }
  if (seg == 0) {
    float d0 = fmaxf(a[0], 0.f), d1 = fmaxf(a[1], 0.f), d2 = fmaxf(a[2], 0.f);
    float r0 = 1.f/(d0 + 1e-8f), r1 = 1.f/(d1 + 1e-8f), r2 = 1.f/(d2 + 1e-8f);
    float s = (r0 + r1) + r2;
    size_t o = ((size_t)b * Mq + q) * 3;
    oidx[o+0] = id[0]; oidx[o+1] = id[1]; oidx[o+2] = id[2];
    ow[o+0] = r0/s; ow[o+1] = r1/s; ow[o+2] = r2/s;
  }
}

// ------------------------------------------------------------------
// Edge-conv neighbor mean: hbar[p] = [mean_k x[n_k], mean_k (pos_p - pos_nk), mean_k |rel|^2]
__global__ void hbar_kernel(const float* __restrict__ x, const float* __restrict__ pos,
                            const int* __restrict__ idx, int Mlvl, int C, int B,
                            float* __restrict__ out)
{
  const int Ct = C + 4;
  const int tot = B * Mlvl * Ct;
  int e = blockIdx.x * 256 + threadIdx.x;
  if (e >= tot) return;
  const int c  = e % Ct;
  const int p  = e / Ct;
  const int b  = p / Mlvl;
  const int lm = p % Mlvl;
  const int* ip = idx + (size_t)p * 16;
  float s = 0.f;
  if (c < C) {
    const float* xb = x + (size_t)b * Mlvl * C;
#pragma unroll 4
    for (int k = 0; k < 16; ++k) s += xb[(size_t)ip[k] * C + c];
  } else if (c < C + 3) {
    const int dd = c - C;
    const float* pb = pos + (size_t)b * Mlvl * 3;
    const float pc = pb[lm*3 + dd];
#pragma unroll 4
    for (int k = 0; k < 16; ++k) s += pc - pb[ip[k]*3 + dd];
  } else {
    const float* pb = pos + (size_t)b * Mlvl * 3;
    const float px = pb[lm*3+0], py = pb[lm*3+1], pz = pb[lm*3+2];
#pragma unroll 4
    for (int k = 0; k < 16; ++k) {
      int n = ip[k];
      float dx = px - pb[n*3+0], dy = py - pb[n*3+1], dz = pz - pb[n*3+2];
      s += (dx*dx + dy*dy) + dz*dz;
    }
  }
  out[e] = s * 0.0625f;
}

// ------------------------------------------------------------------
__global__ void interp_kernel(const float* __restrict__ f, const int* __restrict__ nidx,
                              const float* __restrict__ nw, int Mq, int Msub, int C, int B,
                              float* __restrict__ out)
{
  const int tot = B * Mq * C;
  int e = blockIdx.x * 256 + threadIdx.x;
  if (e >= tot) return;
  const int c = e % C;
  const int p = e / C;
  const int b = p / Mq;
  const float* fb = f + (size_t)b * Msub * C;
  const int* ip   = nidx + (size_t)p * 3;
  const float* wp = nw   + (size_t)p * 3;
  out[e] = (wp[0] * fb[(size_t)ip[0]*C + c] + wp[1] * fb[(size_t)ip[1]*C + c])
         +  wp[2] * fb[(size_t)ip[2]*C + c];
}

// ------------------------------------------------------------------
__global__ void gather_kernel(const float* __restrict__ src, const int* __restrict__ idx,
                              int Mq, int Msrc, int C, int B, float* __restrict__ dst)
{
  const int tot = B * Mq * C;
  int e = blockIdx.x * 256 + threadIdx.x;
  if (e >= tot) return;
  const int c = e % C;
  const int p = e / C;
  const int b = p / Mq;
  dst[e] = src[((size_t)b * Msrc + idx[p]) * C + c];
}

// ------------------------------------------------------------------
// Fused GEMM: out[M,F] = act( A[M,Ka]@W1[Ka,F] + B2[M,Kb]@W2[Kb,F] + bias )
// 64x64 tile, BK=16, 256 threads, 4x4 micro-tile. M,F multiples of 64; K zero-padded.
__global__ __launch_bounds__(256) void gemm_kernel(const float* __restrict__ A, int Ka,
                                                   const float* __restrict__ B2, int Kb,
                                                   const float* __restrict__ W1,
                                                   const float* __restrict__ W2,
                                                   const float* __restrict__ bias,
                                                   float* __restrict__ out,
                                                   int M, int F, int act)
{
  __shared__ __align__(16) float As[16][64];
  __shared__ __align__(16) float Ws[16][64];
  const int tid  = threadIdx.x;
  const int row0 = blockIdx.x * 64;
  const int col0 = blockIdx.y * 64;
  const int tx = tid & 15, ty = tid >> 4;
  const int K = Ka + Kb;
  float acc[4][4] = {};
  for (int k0 = 0; k0 < K; k0 += 16) {
#pragma unroll
    for (int i = 0; i < 4; ++i) {
      int e = tid + i * 256;
      int m = e & 63, kk = e >> 6;
      int k = k0 + kk;
      float v = 0.f;
      if (k < Ka)     v = A [(size_t)(row0 + m) * Ka + k];
      else if (k < K) v = B2[(size_t)(row0 + m) * Kb + (k - Ka)];
      As[kk][m] = v;
      float wv = 0.f;
      if (k < Ka)     wv = W1[(size_t)k * F + col0 + m];
      else if (k < K) wv = W2[(size_t)(k - Ka) * F + col0 + m];
      Ws[kk][m] = wv;
    }
    __syncthreads();
#pragma unroll
    for (int kk = 0; kk < 16; ++kk) {
      const float4 a4 = *reinterpret_cast<const float4*>(&As[kk][ty * 4]);
      const float4 b4 = *reinterpret_cast<const float4*>(&Ws[kk][tx * 4]);
      const float av[4] = {a4.x, a4.y, a4.z, a4.w};
      const float bv[4] = {b4.x, b4.y, b4.z, b4.w};
#pragma unroll
      for (int i2 = 0; i2 < 4; ++i2)
#pragma unroll
        for (int j2 = 0; j2 < 4; ++j2)
          acc[i2][j2] = fmaf(av[i2], bv[j2], acc[i2][j2]);
    }
    __syncthreads();
  }
#pragma unroll
  for (int i2 = 0; i2 < 4; ++i2) {
    int r = row0 + ty * 4 + i2;
#pragma unroll
    for (int j2 = 0; j2 < 4; ++j2) {
      int cc = col0 + tx * 4 + j2;
      float v = acc[i2][j2];
      if (bias) v += bias[cc];
      if (act)  v = leakyf(v);
      out[(size_t)r * F + cc] = v;
    }
  }
}

// ------------------------------------------------------------------
extern "C" void kernel_launch(void* const* d_in, const int* in_sizes, int n_in,
                              void* d_out, int out_size, void* d_ws, size_t ws_size,
                              hipStream_t stream)
{
  (void)in_sizes; (void)n_in; (void)out_size; (void)ws_size;
  const float* x          = (const float*)d_in[0];   // [2,8192,4]
  const float* pos        = (const float*)d_in[1];   // [2,8192,3]
  const float* w_self0    = (const float*)d_in[2];   // [4,64]
  const float* w_edge0    = (const float*)d_in[3];   // [8,64]
  const float* w_self1    = (const float*)d_in[4];   // [64,128]
  const float* w_edge1    = (const float*)d_in[5];   // [68,128]
  const float* w_self2    = (const float*)d_in[6];   // [128,256]
  const float* w_edge2    = (const float*)d_in[7];   // [132,256]
  const float* w_up1      = (const float*)d_in[8];   // [384,128]
  const float* b_up1      = (const float*)d_in[9];   // [128]
  const float* w_upc1s    = (const float*)d_in[10];  // [128,128]
  const float* w_upc1e    = (const float*)d_in[11];  // [132,128]
  const float* w_up0      = (const float*)d_in[12];  // [192,64]
  const float* b_up0      = (const float*)d_in[13];  // [64]
  const float* w_upc0s    = (const float*)d_in[14];  // [64,64]
  const float* w_upc0e    = (const float*)d_in[15];  // [68,64]
  const float* w_out      = (const float*)d_in[16];  // [64,128]
  const float* b_out      = (const float*)d_in[17];  // [128]
  float* out = (float*)d_out;                        // [2,8192,128]

  char* ws = (char*)d_ws;
  size_t off = 0;
  auto alloc = [&](size_t nbytes) -> void* {
    off = (off + 255) & ~(size_t)255;
    void* p = ws + off;
    off += nbytes;
    return p;
  };
  int*    knn0   = (int*)   alloc((size_t)2*8192*16*4);
  int*    knn1   = (int*)   alloc((size_t)2*4096*16*4);
  int*    knn2   = (int*)   alloc((size_t)2*2048*16*4);
  int*    idx1   = (int*)   alloc((size_t)2*4096*4);
  int*    idx2   = (int*)   alloc((size_t)2*2048*4);
  float*  pos1   = (float*) alloc((size_t)2*4096*3*4);
  float*  pos2   = (float*) alloc((size_t)2*2048*3*4);
  float4* pp0    = (float4*)alloc((size_t)2*8192*16);
  float4* pp1    = (float4*)alloc((size_t)2*4096*16);
  float4* pp2    = (float4*)alloc((size_t)2*2048*16);
  float*  feat0  = (float*) alloc((size_t)2*8192*64*4);
  float*  feat0g = (float*) alloc((size_t)2*4096*64*4);
  float*  feat1  = (float*) alloc((size_t)2*4096*128*4);
  float*  feat1g = (float*) alloc((size_t)2*2048*128*4);
  float*  feat2  = (float*) alloc((size_t)2*2048*256*4);
  int*    nn1i   = (int*)   alloc((size_t)2*4096*3*4);
  float*  nn1w   = (float*) alloc((size_t)2*4096*3*4);
  int*    nn0i   = (int*)   alloc((size_t)2*8192*3*4);
  float*  nn0w   = (float*) alloc((size_t)2*8192*3*4);
  float*  interp = (float*) alloc((size_t)2*4096*256*4);  // reused for interp0 (same size)
  float*  hbar   = (float*) alloc((size_t)2*8192*68*4);   // max of all hbar stages
  float*  fupa   = (float*) alloc((size_t)2*4096*128*4);  // fup1a, later fup0a (same size)
  float*  fup1   = (float*) alloc((size_t)2*4096*128*4);
  float*  fout   = (float*) alloc((size_t)2*8192*64*4);
  // pruned-FPS scratch (level 1: N=8192/NG=128, level 2: N=4096/NG=64)
  float*  m1x  = (float*) alloc((size_t)2*8192*4);
  float*  m1y  = (float*) alloc((size_t)2*8192*4);
  float*  m1z  = (float*) alloc((size_t)2*8192*4);
  unsigned* m1iv = (unsigned*)alloc((size_t)2*8192*4);
  float4* m1gc = (float4*)alloc((size_t)2*128*16);
  u64*    m1gk = (u64*)   alloc((size_t)2*128*8);
  float*  m1ax = (float*) alloc((size_t)2*128*4);
  float*  m2x  = (float*) alloc((size_t)2*4096*4);
  float*  m2y  = (float*) alloc((size_t)2*4096*4);
  float*  m2z  = (float*) alloc((size_t)2*4096*4);
  unsigned* m2iv = (unsigned*)alloc((size_t)2*4096*4);
  float4* m2gc = (float4*)alloc((size_t)2*64*16);
  u64*    m2gk = (u64*)   alloc((size_t)2*64*8);
  float*  m2ax = (float*) alloc((size_t)2*64*4);

  // --- packed pos level 0 + FPS prep level 1 ---
  pack_kernel<<<64, 256, 0, stream>>>(pos, 2*8192, pp0);
  fps_prep_kernel<8192><<<2, 512, 0, stream>>>(pos, m1x, m1y, m1z, m1iv, m1gc, m1gk, m1ax);
  // --- level 0: knn + edge conv ---
  knn_kernel<16><<<dim3(512, 2), 256, 0, stream>>>(pp0, 8192, knn0);
  hbar_kernel<<<512, 256, 0, stream>>>(x, pos, knn0, 8192, 4, 2, hbar);
  gemm_kernel<<<dim3(256, 1), 256, 0, stream>>>(x, 4, hbar, 8, w_self0, w_edge0, nullptr,
                                                feat0, 16384, 64, 1);
  // --- FPS level 1 + downsample ---
  fps_kernel<8192, 4096><<<2, 256, 0, stream>>>(pos, m1x, m1y, m1z, m1iv, m1gc, m1gk, m1ax,
                                                idx1, pos1, pp1);
  fps_prep_kernel<4096><<<2, 512, 0, stream>>>(pos1, m2x, m2y, m2z, m2iv, m2gc, m2gk, m2ax);
  gather_kernel<<<2048, 256, 0, stream>>>(feat0, idx1, 4096, 8192, 64, 2, feat0g);
  knn_kernel<16><<<dim3(256, 2), 256, 0, stream>>>(pp1, 4096, knn1);
  hbar_kernel<<<2176, 256, 0, stream>>>(feat0g, pos1, knn1, 4096, 64, 2, hbar);
  gemm_kernel<<<dim3(128, 2), 256, 0, stream>>>(feat0g, 64, hbar, 68, w_self1, w_edge1, nullptr,
                                                feat1, 8192, 128, 1);
  // --- FPS level 2 + downsample ---
  fps_kernel<4096, 2048><<<2, 256, 0, stream>>>(pos1, m2x, m2y, m2z, m2iv, m2gc, m2gk, m2ax,
                                                idx2, pos2, pp2);
  gather_kernel<<<2048, 256, 0, stream>>>(feat1, idx2, 2048, 4096, 128, 2, feat1g);
  knn_kernel<16><<<dim3(128, 2), 256, 0, stream>>>(pp2, 2048, knn2);
  hbar_kernel<<<2112, 256, 0, stream>>>(feat1g, pos2, knn2, 2048, 128, 2, hbar);
  gemm_kernel<<<dim3(64, 4), 256, 0, stream>>>(feat1g, 128, hbar, 132, w_self2, w_edge2, nullptr,
                                               feat2, 4096, 256, 1);
  // --- up level 1: interp(feat2)->pos1, concat feat1, linear, edge conv ---
  three_nn_kernel<16><<<dim3(256, 2), 256, 0, stream>>>(pp1, pp2, 4096, 2048, nn1i, nn1w);
  interp_kernel<<<8192, 256, 0, stream>>>(feat2, nn1i, nn1w, 4096, 2048, 256, 2, interp);
  gemm_kernel<<<dim3(128, 2), 256, 0, stream>>>(interp, 256, feat1, 128,
                                                w_up1, w_up1 + (size_t)256 * 128, b_up1,
                                                fupa, 8192, 128, 1);
  hbar_kernel<<<4224, 256, 0, stream>>>(fupa, pos1, knn1, 4096, 128, 2, hbar);
  gemm_kernel<<<dim3(128, 2), 256, 0, stream>>>(fupa, 128, hbar, 132, w_upc1s, w_upc1e, nullptr,
                                                fup1, 8192, 128, 1);
  // --- up level 0: interp(fup1)->pos0, concat feat0, linear, edge conv ---
  three_nn_kernel<16><<<dim3(512, 2), 256, 0, stream>>>(pp0, pp1, 8192, 4096, nn0i, nn0w);
  interp_kernel<<<8192, 256, 0, stream>>>(fup1, nn0i, nn0w, 8192, 4096, 128, 2, interp);
  gemm_kernel<<<dim3(256, 1), 256, 0, stream>>>(interp, 128, feat0, 64,
                                                w_up0, w_up0 + (size_t)128 * 64, b_up0,
                                                fupa, 16384, 64, 1);
  hbar_kernel<<<4352, 256, 0, stream>>>(fupa, pos, knn0, 8192, 64, 2, hbar);
  gemm_kernel<<<dim3(256, 1), 256, 0, stream>>>(fupa, 64, hbar, 68, w_upc0s, w_upc0e, nullptr,
                                                fout, 16384, 64, 1);
  // --- final projection ---
  gemm_kernel<<<dim3(256, 2), 256, 0, stream>>>(fout, 64, nullptr, 0, w_out, nullptr, b_out,
                                                out, 16384, 128, 0);
}

// Round 5
// 6656.855 us; speedup vs baseline: 3.2054x; 3.2054x over previous
//
#include <hip/hip_runtime.h>
#include <cstdint>

typedef unsigned long long u64;

static __device__ __forceinline__ float leakyf(float v) { return v >= 0.f ? v : 0.2f * v; }

// ------------------------------------------------------------------
// Pack [M,3] positions into float4(x,y,z,|p|^2). ss association (x*x+y*y)+z*z
// must match the query-side qq usage in knn/three_nn.
__global__ void pack_kernel(const float* __restrict__ pos, int total, float4* __restrict__ out)
{
  int i = blockIdx.x * 256 + threadIdx.x;
  if (i >= total) return;
  float x = pos[i*3+0], y = pos[i*3+1], z = pos[i*3+2];
  out[i] = make_float4(x, y, z, (x*x + y*y) + z*z);
}

// ------------------------------------------------------------------
// DPP wave64 reductions (rocPRIM pattern): row_shr 1/2/4/8 + row_bcast15/31
// accumulate the reduce into lane 63; readlane(63) broadcasts via SGPR.
// update_dpp(old=x, src=x, ctrl, 0xF, 0xF, false): lanes with no source keep x,
// so fmax/umax against it is a no-op (identity) — exact.
template<int CTRL>
static __device__ __forceinline__ float dpp_max_f_step(float x)
{
  int y = __builtin_amdgcn_update_dpp(__float_as_int(x), __float_as_int(x), CTRL, 0xF, 0xF, false);
  return fmaxf(x, __int_as_float(y));
}
static __device__ __forceinline__ float wave64_max_f(float x)
{
  x = dpp_max_f_step<0x111>(x);  // row_shr:1
  x = dpp_max_f_step<0x112>(x);  // row_shr:2
  x = dpp_max_f_step<0x114>(x);  // row_shr:4
  x = dpp_max_f_step<0x118>(x);  // row_shr:8
  x = dpp_max_f_step<0x142>(x);  // row_bcast:15
  x = dpp_max_f_step<0x143>(x);  // row_bcast:31
  return __int_as_float(__builtin_amdgcn_readlane(__float_as_int(x), 63));
}
template<int CTRL>
static __device__ __forceinline__ unsigned dpp_max_u_step(unsigned x)
{
  unsigned y = (unsigned)__builtin_amdgcn_update_dpp((int)x, (int)x, CTRL, 0xF, 0xF, false);
  return x > y ? x : y;
}
static __device__ __forceinline__ unsigned wave64_max_u(unsigned x)
{
  x = dpp_max_u_step<0x111>(x);
  x = dpp_max_u_step<0x112>(x);
  x = dpp_max_u_step<0x114>(x);
  x = dpp_max_u_step<0x118>(x);
  x = dpp_max_u_step<0x142>(x);
  x = dpp_max_u_step<0x143>(x);
  return (unsigned)__builtin_amdgcn_readlane((int)x, 63);
}

// ------------------------------------------------------------------
// Furthest point sampling (exact, matches jax scan semantics):
// out[0]=0; for it in 1..NP-1: dists=min(dists, d(.,pos[out[it-1]])); out[it]=argmax (first max).
// One block (512 threads = 8 waves) per batch, dense update (R3 structure).
// Argmax: per-thread strict-> scan (keeps lowest idx on ties), then DPP wave max of d,
// ballot-free tie-break: DPP wave max of (d==wmax ? iv : 0) with iv=0xFFFFFFFF-idx
// (max iv == min idx == first occurrence). Wave partials combined via u64 keys in LDS
// (f32 bits of d are monotone as u32 for d>=0), single barrier/iter, double-buffered.
// Selection sequence bit-identical to the R3 dense version.
template<int N, int NPOINT>
__global__ __launch_bounds__(512) void fps_kernel(const float* __restrict__ pos,
                                                  int* __restrict__ out_idx,
                                                  float* __restrict__ out_pos,
                                                  float4* __restrict__ out_pp)
{
  constexpr int BLOCK = 512;
  constexpr int NPT = N / BLOCK;
  const int b = blockIdx.x;
  const float* P = pos + (size_t)b * N * 3;
  int* oi = out_idx + (size_t)b * NPOINT;
  float* op = out_pos + (size_t)b * NPOINT * 3;
  float4* opp = out_pp + (size_t)b * NPOINT;

  __shared__ float4 spos[N];
  __shared__ u64 redk[2][8];

  const int t = threadIdx.x;
  const int lane = t & 63;
  const int wv = t >> 6;

  float px[NPT], py[NPT], pz[NPT], dist[NPT];
  unsigned iv[NPT];  // 0xFFFFFFFF - global_idx (tie-break payload)
#pragma unroll
  for (int j = 0; j < NPT; ++j) {
    int i = t + j * BLOCK;
    float x = P[i*3+0], y = P[i*3+1], z = P[i*3+2];
    spos[i] = make_float4(x, y, z, (x*x + y*y) + z*z);
    px[j] = x; py[j] = y; pz[j] = z; dist[j] = 1e10f;
    iv[j] = 0xFFFFFFFFu - (unsigned)i;
  }
  if (t == 0) oi[0] = 0;
  __syncthreads();

  int far = 0;
  for (int it = 1; it < NPOINT; ++it) {
    const float4 c = spos[far];              // one b128 broadcast read
    if (t == ((it - 1) & (BLOCK - 1))) {     // emit sample it-1 (coords = current center)
      op[(it-1)*3+0] = c.x; op[(it-1)*3+1] = c.y; op[(it-1)*3+2] = c.z;
      opp[it-1] = c;
    }
    float bd = -1.f; unsigned biv = 0u;
#pragma unroll
    for (int j = 0; j < NPT; ++j) {
      float dx = px[j] - c.x, dy = py[j] - c.y, dz = pz[j] - c.z;
      float d  = fmaf(dz, dz, fmaf(dy, dy, dx * dx));
      float nd = fminf(dist[j], d);
      dist[j] = nd;
      bool bt = nd > bd;                     // strict >: ties keep earlier j = lower idx
      bd  = bt ? nd : bd;
      biv = bt ? iv[j] : biv;
    }
    // wave argmax: DPP max of d, then DPP max of tie-filtered iv (min idx)
    const float wmax = wave64_max_f(bd);
    const unsigned cand = (bd == wmax) ? biv : 0u;   // fmax returns an input => bitwise == sound
    const unsigned wiv = wave64_max_u(cand);
    const int par = it & 1;
    if (lane == 0) redk[par][wv] = ((u64)__float_as_uint(wmax) << 32) | (u64)wiv;
    __syncthreads();
    // all threads combine the 8 wave partials in VALU (u64 max == lexicographic)
    u64 key = ((u64)__float_as_uint(wmax) << 32) | (u64)wiv;
#pragma unroll
    for (int w2 = 0; w2 < 8; ++w2) {
      u64 o = redk[par][w2];
      if (o > key) key = o;
    }
    far = (int)(0xFFFFFFFFu - (unsigned)(key & 0xFFFFFFFFull));
    if (t == 0) oi[it] = far;
  }
  // flush the last sample
  {
    const float4 c = spos[far];
    if (t == ((NPOINT - 1) & (BLOCK - 1))) {
      op[(NPOINT-1)*3+0] = c.x; op[(NPOINT-1)*3+1] = c.y; op[(NPOINT-1)*3+2] = c.z;
      opp[NPOINT-1] = c;
    }
  }
}

// ------------------------------------------------------------------
// Self-KNN (K=16), stable (d, idx) selection identical to lax.top_k(-d).
// G=16 segments per query; per-seg sorted top-16 in registers; segments merged
// in-wave via shfl_xor bitonic rounds with lexicographic (d, idx) comparator.
template<int G>
__global__ __launch_bounds__(256) void knn_kernel(const float4* __restrict__ pp, int M,
                                                  int* __restrict__ out)
{
  const int b = blockIdx.y;
  const float4* P = pp + (size_t)b * M;
  const int tid = threadIdx.x;
  constexpr int QPB = 256 / G;
  const int q = blockIdx.x * QPB + tid / G;
  const int seg = tid % G;

  __shared__ float4 tile[512];

  const float4 qp = P[q];
  const float qx = qp.x, qy = qp.y, qz = qp.z, qq = qp.w;

  float a[16]; int id[16];
#pragma unroll
  for (int j = 0; j < 16; ++j) { a[j] = 3.4e38f; id[j] = 0x7fffffff; }

  for (int t0 = 0; t0 < M; t0 += 512) {
    __syncthreads();
    tile[tid]       = P[t0 + tid];
    tile[tid + 256] = P[t0 + tid + 256];
    __syncthreads();
#pragma unroll 4
    for (int i = seg; i < 512; i += G) {
      float4 c = tile[i];
      float d = (qq + c.w) - 2.f * ((qx*c.x + qy*c.y) + qz*c.z);
      int gi = t0 + i;
      if (d < a[15]) {               // insertion, stable: ties keep earlier idx
        bool cc[16];
#pragma unroll
        for (int j = 0; j < 16; ++j) cc[j] = d < a[j];
#pragma unroll
        for (int j = 15; j >= 1; --j) {
          a[j]  = cc[j-1] ? a[j-1]  : (cc[j] ? d  : a[j]);
          id[j] = cc[j-1] ? id[j-1] : (cc[j] ? gi : id[j]);
        }
        if (cc[0]) { a[0] = d; id[0] = gi; }
      }
    }
  }
  // butterfly merge across G segments
#pragma unroll
  for (int s = G/2; s >= 1; s >>= 1) {
    float bd[16]; int bi[16];
#pragma unroll
    for (int j = 0; j < 16; ++j) { bd[j] = __shfl_xor(a[j], s); bi[j] = __shfl_xor(id[j], s); }
#pragma unroll
    for (int j = 0; j < 16; ++j) {       // lower half of bitonic 32-seq [a asc | b desc]
      float od = bd[15-j]; int ob = bi[15-j];
      bool take = (od < a[j]) || (od == a[j] && ob < id[j]);
      a[j]  = take ? od : a[j];
      id[j] = take ? ob : id[j];
    }
#pragma unroll
    for (int st = 8; st >= 1; st >>= 1) { // bitonic merge
#pragma unroll
      for (int j = 0; j < 16; ++j) {
        if ((j & st) == 0) {
          const int j2 = j + st;
          bool sw = (a[j2] < a[j]) || (a[j2] == a[j] && id[j2] < id[j]);
          float lod = sw ? a[j2] : a[j];  int loi = sw ? id[j2] : id[j];
          float hid = sw ? a[j]  : a[j2]; int hii = sw ? id[j]  : id[j2];
          a[j] = lod; id[j] = loi; a[j2] = hid; id[j2] = hii;
        }
      }
    }
  }
  if (seg == 0) {
    int* opp = out + ((size_t)b * M + q) * 16;
#pragma unroll
    for (int j = 0; j < 16; ++j) opp[j] = id[j];
  }
}

// ------------------------------------------------------------------
// three_nn + interpolation weights. Same G-segmented structure with register
// top-4 lists (4th slot only to make the bitonic trick power-of-two).
template<int G>
__global__ __launch_bounds__(256) void three_nn_kernel(const float4* __restrict__ qpp,
                                                       const float4* __restrict__ kpp,
                                                       int Mq, int Mk,
                                                       int* __restrict__ oidx, float* __restrict__ ow)
{
  const int b = blockIdx.y;
  const float4* Q  = qpp + (size_t)b * Mq;
  const float4* Kp = kpp + (size_t)b * Mk;
  const int tid = threadIdx.x;
  constexpr int QPB = 256 / G;
  const int q = blockIdx.x * QPB + tid / G;
  const int seg = tid % G;

  __shared__ float4 tile[512];

  const float4 qp = Q[q];
  const float qx = qp.x, qy = qp.y, qz = qp.z, qq = qp.w;

  float a[4]; int id[4];
#pragma unroll
  for (int j = 0; j < 4; ++j) { a[j] = 3.4e38f; id[j] = 0x7fffffff; }

  for (int t0 = 0; t0 < Mk; t0 += 512) {
    __syncthreads();
    tile[tid]       = Kp[t0 + tid];
    tile[tid + 256] = Kp[t0 + tid + 256];
    __syncthreads();
#pragma unroll 4
    for (int i = seg; i < 512; i += G) {
      float4 c = tile[i];
      float d = (qq + c.w) - 2.f * ((qx*c.x + qy*c.y) + qz*c.z);
      int gi = t0 + i;
      if (d < a[3]) {
        bool c0 = d < a[0], c1 = d < a[1], c2 = d < a[2];
        a[3]  = c2 ? a[2]  : d;                id[3] = c2 ? id[2] : gi;
        a[2]  = c1 ? a[1]  : (c2 ? d  : a[2]); id[2] = c1 ? id[1] : (c2 ? gi : id[2]);
        a[1]  = c0 ? a[0]  : (c1 ? d  : a[1]); id[1] = c0 ? id[0] : (c1 ? gi : id[1]);
        if (c0) { a[0] = d; id[0] = gi; }
      }
    }
  }
#pragma unroll
  for (int s = G/2; s >= 1; s >>= 1) {
    float bd[4]; int bi[4];
#pragma unroll
    for (int j = 0; j < 4; ++j) { bd[j] = __shfl_xor(a[j], s); bi[j] = __shfl_xor(id[j], s); }
#pragma unroll
    for (int j = 0; j < 4; ++j) {
      float od = bd[3-j]; int ob = bi[3-j];
      bool take = (od < a[j]) || (od == a[j] && ob < id[j]);
      a[j]  = take ? od : a[j];
      id[j] = take ? ob : id[j];
    }
#pragma unroll
    for (int st = 2; st >= 1; st >>= 1) {
#pragma unroll
      for (int j = 0; j < 4; ++j) {
        if ((j & st) == 0) {
          const int j2 = j + st;
          bool sw = (a[j2] < a[j]) || (a[j2] == a[j] && id[j2] < id[j]);
          float lod = sw ? a[j2] : a[j];  int loi = sw ? id[j2] : id[j];
          float hid = sw ? a[j]  : a[j2]; int hii = sw ? id[j]  : id[j2];
          a[j] = lod; id[j] = loi; a[j2] = hid; id[j2] = hii;
        }
      }
    }
  }
  if (seg == 0) {
    float d0 = fmaxf(a[0], 0.f), d1 = fmaxf(a[1], 0.f), d2 = fmaxf(a[2], 0.f);
    float r0 = 1.f/(d0 + 1e-8f), r1 = 1.f/(d1 + 1e-8f), r2 = 1.f/(d2 + 1e-8f);
    float s = (r0 + r1) + r2;
    size_t o = ((size_t)b * Mq + q) * 3;
    oidx[o+0] = id[0]; oidx[o+1] = id[1]; oidx[o+2] = id[2];
    ow[o+0] = r0/s; ow[o+1] = r1/s; ow[o+2] = r2/s;
  }
}

// ------------------------------------------------------------------
// Edge-conv neighbor mean: hbar[p] = [mean_k x[n_k], mean_k (pos_p - pos_nk), mean_k |rel|^2]
__global__ void hbar_kernel(const float* __restrict__ x, const float* __restrict__ pos,
                            const int* __restrict__ idx, int Mlvl, int C, int B,
                            float* __restrict__ out)
{
  const int Ct = C + 4;
  const int tot = B * Mlvl * Ct;
  int e = blockIdx.x * 256 + threadIdx.x;
  if (e >= tot) return;
  const int c  = e % Ct;
  const int p  = e / Ct;
  const int b  = p / Mlvl;
  const int lm = p % Mlvl;
  const int* ip = idx + (size_t)p * 16;
  float s = 0.f;
  if (c < C) {
    const float* xb = x + (size_t)b * Mlvl * C;
#pragma unroll 4
    for (int k = 0; k < 16; ++k) s += xb[(size_t)ip[k] * C + c];
  } else if (c < C + 3) {
    const int dd = c - C;
    const float* pb = pos + (size_t)b * Mlvl * 3;
    const float pc = pb[lm*3 + dd];
#pragma unroll 4
    for (int k = 0; k < 16; ++k) s += pc - pb[ip[k]*3 + dd];
  } else {
    const float* pb = pos + (size_t)b * Mlvl * 3;
    const float px = pb[lm*3+0], py = pb[lm*3+1], pz = pb[lm*3+2];
#pragma unroll 4
    for (int k = 0; k < 16; ++k) {
      int n = ip[k];
      float dx = px - pb[n*3+0], dy = py - pb[n*3+1], dz = pz - pb[n*3+2];
      s += (dx*dx + dy*dy) + dz*dz;
    }
  }
  out[e] = s * 0.0625f;
}

// ------------------------------------------------------------------
__global__ void interp_kernel(const float* __restrict__ f, const int* __restrict__ nidx,
                              const float* __restrict__ nw, int Mq, int Msub, int C, int B,
                              float* __restrict__ out)
{
  const int tot = B * Mq * C;
  int e = blockIdx.x * 256 + threadIdx.x;
  if (e >= tot) return;
  const int c = e % C;
  const int p = e / C;
  const int b = p / Mq;
  const float* fb = f + (size_t)b * Msub * C;
  const int* ip   = nidx + (size_t)p * 3;
  const float* wp = nw   + (size_t)p * 3;
  out[e] = (wp[0] * fb[(size_t)ip[0]*C + c] + wp[1] * fb[(size_t)ip[1]*C + c])
         +  wp[2] * fb[(size_t)ip[2]*C + c];
}

// ------------------------------------------------------------------
__global__ void gather_kernel(const float* __restrict__ src, const int* __restrict__ idx,
                              int Mq, int Msrc, int C, int B, float* __restrict__ dst)
{
  const int tot = B * Mq * C;
  int e = blockIdx.x * 256 + threadIdx.x;
  if (e >= tot) return;
  const int c = e % C;
  const int p = e / C;
  const int b = p / Mq;
  dst[e] = src[((size_t)b * Msrc + idx[p]) * C + c];
}

// ------------------------------------------------------------------
// Fused GEMM: out[M,F] = act( A[M,Ka]@W1[Ka,F] + B2[M,Kb]@W2[Kb,F] + bias )
// 64x64 tile, BK=16, 256 threads, 4x4 micro-tile. M,F multiples of 64; K zero-padded.
__global__ __launch_bounds__(256) void gemm_kernel(const float* __restrict__ A, int Ka,
                                                   const float* __restrict__ B2, int Kb,
                                                   const float* __restrict__ W1,
                                                   const float* __restrict__ W2,
                                                   const float* __restrict__ bias,
                                                   float* __restrict__ out,
                                                   int M, int F, int act)
{
  __shared__ __align__(16) float As[16][64];
  __shared__ __align__(16) float Ws[16][64];
  const int tid  = threadIdx.x;
  const int row0 = blockIdx.x * 64;
  const int col0 = blockIdx.y * 64;
  const int tx = tid & 15, ty = tid >> 4;
  const int K = Ka + Kb;
  float acc[4][4] = {};
  for (int k0 = 0; k0 < K; k0 += 16) {
#pragma unroll
    for (int i = 0; i < 4; ++i) {
      int e = tid + i * 256;
      int m = e & 63, kk = e >> 6;
      int k = k0 + kk;
      float v = 0.f;
      if (k < Ka)     v = A [(size_t)(row0 + m) * Ka + k];
      else if (k < K) v = B2[(size_t)(row0 + m) * Kb + (k - Ka)];
      As[kk][m] = v;
      float wv = 0.f;
      if (k < Ka)     wv = W1[(size_t)k * F + col0 + m];
      else if (k < K) wv = W2[(size_t)(k - Ka) * F + col0 + m];
      Ws[kk][m] = wv;
    }
    __syncthreads();
#pragma unroll
    for (int kk = 0; kk < 16; ++kk) {
      const float4 a4 = *reinterpret_cast<const float4*>(&As[kk][ty * 4]);
      const float4 b4 = *reinterpret_cast<const float4*>(&Ws[kk][tx * 4]);
      const float av[4] = {a4.x, a4.y, a4.z, a4.w};
      const float bv[4] = {b4.x, b4.y, b4.z, b4.w};
#pragma unroll
      for (int i2 = 0; i2 < 4; ++i2)
#pragma unroll
        for (int j2 = 0; j2 < 4; ++j2)
          acc[i2][j2] = fmaf(av[i2], bv[j2], acc[i2][j2]);
    }
    __syncthreads();
  }
#pragma unroll
  for (int i2 = 0; i2 < 4; ++i2) {
    int r = row0 + ty * 4 + i2;
#pragma unroll
    for (int j2 = 0; j2 < 4; ++j2) {
      int cc = col0 + tx * 4 + j2;
      float v = acc[i2][j2];
      if (bias) v += bias[cc];
      if (act)  v = leakyf(v);
      out[(size_t)r * F + cc] = v;
    }
  }
}

// ------------------------------------------------------------------
extern "C" void kernel_launch(void* const* d_in, const int* in_sizes, int n_in,
                              void* d_out, int out_size, void* d_ws, size_t ws_size,
                              hipStream_t stream)
{
  (void)in_sizes; (void)n_in; (void)out_size; (void)ws_size;
  const float* x          = (const float*)d_in[0];   // [2,8192,4]
  const float* pos        = (const float*)d_in[1];   // [2,8192,3]
  const float* w_self0    = (const float*)d_in[2];   // [4,64]
  const float* w_edge0    = (const float*)d_in[3];   // [8,64]
  const float* w_self1    = (const float*)d_in[4];   // [64,128]
  const float* w_edge1    = (const float*)d_in[5];   // [68,128]
  const float* w_self2    = (const float*)d_in[6];   // [128,256]
  const float* w_edge2    = (const float*)d_in[7];   // [132,256]
  const float* w_up1      = (const float*)d_in[8];   // [384,128]
  const float* b_up1      = (const float*)d_in[9];   // [128]
  const float* w_upc1s    = (const float*)d_in[10];  // [128,128]
  const float* w_upc1e    = (const float*)d_in[11];  // [132,128]
  const float* w_up0      = (const float*)d_in[12];  // [192,64]
  const float* b_up0      = (const float*)d_in[13];  // [64]
  const float* w_upc0s    = (const float*)d_in[14];  // [64,64]
  const float* w_upc0e    = (const float*)d_in[15];  // [68,64]
  const float* w_out      = (const float*)d_in[16];  // [64,128]
  const float* b_out      = (const float*)d_in[17];  // [128]
  float* out = (float*)d_out;                        // [2,8192,128]

  char* ws = (char*)d_ws;
  size_t off = 0;
  auto alloc = [&](size_t nbytes) -> void* {
    off = (off + 255) & ~(size_t)255;
    void* p = ws + off;
    off += nbytes;
    return p;
  };
  int*    knn0   = (int*)   alloc((size_t)2*8192*16*4);
  int*    knn1   = (int*)   alloc((size_t)2*4096*16*4);
  int*    knn2   = (int*)   alloc((size_t)2*2048*16*4);
  int*    idx1   = (int*)   alloc((size_t)2*4096*4);
  int*    idx2   = (int*)   alloc((size_t)2*2048*4);
  float*  pos1   = (float*) alloc((size_t)2*4096*3*4);
  float*  pos2   = (float*) alloc((size_t)2*2048*3*4);
  float4* pp0    = (float4*)alloc((size_t)2*8192*16);
  float4* pp1    = (float4*)alloc((size_t)2*4096*16);
  float4* pp2    = (float4*)alloc((size_t)2*2048*16);
  float*  feat0  = (float*) alloc((size_t)2*8192*64*4);
  float*  feat0g = (float*) alloc((size_t)2*4096*64*4);
  float*  feat1  = (float*) alloc((size_t)2*4096*128*4);
  float*  feat1g = (float*) alloc((size_t)2*2048*128*4);
  float*  feat2  = (float*) alloc((size_t)2*2048*256*4);
  int*    nn1i   = (int*)   alloc((size_t)2*4096*3*4);
  float*  nn1w   = (float*) alloc((size_t)2*4096*3*4);
  int*    nn0i   = (int*)   alloc((size_t)2*8192*3*4);
  float*  nn0w   = (float*) alloc((size_t)2*8192*3*4);
  float*  interp = (float*) alloc((size_t)2*4096*256*4);  // reused for interp0 (same size)
  float*  hbar   = (float*) alloc((size_t)2*8192*68*4);   // max of all hbar stages
  float*  fupa   = (float*) alloc((size_t)2*4096*128*4);  // fup1a, later fup0a (same size)
  float*  fup1   = (float*) alloc((size_t)2*4096*128*4);
  float*  fout   = (float*) alloc((size_t)2*8192*64*4);

  // --- packed pos level 0 ---
  pack_kernel<<<64, 256, 0, stream>>>(pos, 2*8192, pp0);
  // --- level 0: knn + edge conv ---
  knn_kernel<16><<<dim3(512, 2), 256, 0, stream>>>(pp0, 8192, knn0);
  hbar_kernel<<<512, 256, 0, stream>>>(x, pos, knn0, 8192, 4, 2, hbar);
  gemm_kernel<<<dim3(256, 1), 256, 0, stream>>>(x, 4, hbar, 8, w_self0, w_edge0, nullptr,
                                                feat0, 16384, 64, 1);
  // --- FPS level 1 + downsample ---
  fps_kernel<8192, 4096><<<2, 512, 0, stream>>>(pos, idx1, pos1, pp1);
  gather_kernel<<<2048, 256, 0, stream>>>(feat0, idx1, 4096, 8192, 64, 2, feat0g);
  knn_kernel<16><<<dim3(256, 2), 256, 0, stream>>>(pp1, 4096, knn1);
  hbar_kernel<<<2176, 256, 0, stream>>>(feat0g, pos1, knn1, 4096, 64, 2, hbar);
  gemm_kernel<<<dim3(128, 2), 256, 0, stream>>>(feat0g, 64, hbar, 68, w_self1, w_edge1, nullptr,
                                                feat1, 8192, 128, 1);
  // --- FPS level 2 + downsample ---
  fps_kernel<4096, 2048><<<2, 512, 0, stream>>>(pos1, idx2, pos2, pp2);
  gather_kernel<<<2048, 256, 0, stream>>>(feat1, idx2, 2048, 4096, 128, 2, feat1g);
  knn_kernel<16><<<dim3(128, 2), 256, 0, stream>>>(pp2, 2048, knn2);
  hbar_kernel<<<2112, 256, 0, stream>>>(feat1g, pos2, knn2, 2048, 128, 2, hbar);
  gemm_kernel<<<dim3(64, 4), 256, 0, stream>>>(feat1g, 128, hbar, 132, w_self2, w_edge2, nullptr,
                                               feat2, 4096, 256, 1);
  // --- up level 1: interp(feat2)->pos1, concat feat1, linear, edge conv ---
  three_nn_kernel<16><<<dim3(256, 2), 256, 0, stream>>>(pp1, pp2, 4096, 2048, nn1i, nn1w);
  interp_kernel<<<8192, 256, 0, stream>>>(feat2, nn1i, nn1w, 4096, 2048, 256, 2, interp);
  gemm_kernel<<<dim3(128, 2), 256, 0, stream>>>(interp, 256, feat1, 128,
                                                w_up1, w_up1 + (size_t)256 * 128, b_up1,
                                                fupa, 8192, 128, 1);
  hbar_kernel<<<4224, 256, 0, stream>>>(fupa, pos1, knn1, 4096, 128, 2, hbar);
  gemm_kernel<<<dim3(128, 2), 256, 0, stream>>>(fupa, 128, hbar, 132, w_upc1s, w_upc1e, nullptr,
                                                fup1, 8192, 128, 1);
  // --- up level 0: interp(fup1)->pos0, concat feat0, linear, edge conv ---
  three_nn_kernel<16><<<dim3(512, 2), 256, 0, stream>>>(pp0, pp1, 8192, 4096, nn0i, nn0w);
  interp_kernel<<<8192, 256, 0, stream>>>(fup1, nn0i, nn0w, 8192, 4096, 128, 2, interp);
  gemm_kernel<<<dim3(256, 1), 256, 0, stream>>>(interp, 128, feat0, 64,
                                                w_up0, w_up0 + (size_t)128 * 64, b_up0,
                                                fupa, 16384, 64, 1);
  hbar_kernel<<<4352, 256, 0, stream>>>(fupa, pos, knn0, 8192, 64, 2, hbar);
  gemm_kernel<<<dim3(256, 1), 256, 0, stream>>>(fupa, 64, hbar, 68, w_upc0s, w_upc0e, nullptr,
                                                fout, 16384, 64, 1);
  // --- final projection ---
  gemm_kernel<<<dim3(256, 2), 256, 0, stream>>>(fout, 64, nullptr, 0, w_out, nullptr, b_out,
                                                out, 16384, 128, 0);
}